// Round 1
// baseline (31.952 us; speedup 1.0000x reference)
//
#include <hip/hip_runtime.h>

#define BUF    50
#define MAXK   10
#define NPAD   49        // BUF-1
#define BLK    256
#define HIDDEN 512
#define SEQ    4096

// ---------------------------------------------------------------------------
// Kernel 1: per-position Higuchi fractal dimension (+ time mask).
// One thread per output position p. Block stages close[base-49 .. base+255]
// in LDS, each thread copies its 50-sample window to registers, then the
// k/m/i loops fully unroll (all bounds are compile-time constants).
// ---------------------------------------------------------------------------
__global__ __launch_bounds__(BLK) void fd_kernel(const float* __restrict__ x,
                                                 float* __restrict__ hfd,
                                                 int P) {
    __shared__ float sm[BLK + NPAD];
    const int base = blockIdx.x * BLK;
    for (int j = threadIdx.x; j < BLK + NPAD; j += BLK) {
        const int src = base - NPAD + j;
        sm[j] = (src >= 0 && src < P) ? x[src * 8 + 3] : 0.0f;  // close = x[:,:,3]
    }
    __syncthreads();

    const int p = base + threadIdx.x;
    if (p >= P) return;

    float w[BUF];
#pragma unroll
    for (int j = 0; j < BUF; ++j) w[j] = sm[threadIdx.x + j];

    // log(1..10) precomputed (compile-time table -> folded into code)
    const float logk_tab[MAXK] = {0.0f,        0.69314718f, 1.09861229f,
                                  1.38629436f, 1.60943791f, 1.79175947f,
                                  1.94591015f, 2.07944154f, 2.19722458f,
                                  2.30258509f};

    float Sw = 0.0f, Sx = 0.0f, Sy = 0.0f, Sxx = 0.0f, Sxy = 0.0f;
#pragma unroll
    for (int k = 1; k <= MAXK; ++k) {
        float acc = 0.0f;
#pragma unroll
        for (int m = 0; m < k; ++m) {
            const int Nm = (NPAD - m) / k + 1;  // len(arange(m, BUF, k))
            if (Nm >= 2) {
                float len = 0.0f;
#pragma unroll
                for (int i = 1; i < Nm; ++i) {
                    len += fabsf(w[m + i * k] - w[m + (i - 1) * k]);
                }
                acc += len * ((float)NPAD / ((float)Nm * (float)k));
            }
        }
        const float lk = acc / (float)k;
        if (lk > 0.0f) {
            const float lg = logk_tab[k - 1];
            const float ly = logf(fmaxf(lk, 1e-30f));
            Sw += 1.0f;
            Sx += lg;
            Sy += ly;
            Sxx += lg * lg;
            Sxy += lg * ly;
        }
    }
    const float denom = Sw * Sxx - Sx * Sx;
    const float slope =
        (fabsf(denom) > 1e-12f) ? (Sw * Sxy - Sx * Sy) / denom : 0.0f;
    float fd = (Sw > 1.0f) ? -slope : 0.0f;

    // tmask: positions s < MAX_K within each sequence are zeroed
    const int s = p & (SEQ - 1);
    if (s < MAXK) fd = 0.0f;
    hfd[p] = fd;
}

// ---------------------------------------------------------------------------
// Kernel 2: out[p, h] = relu(hfd[p] * W[h] + b[h]).  Pure HBM-write-bound:
// one thread per float4 of output, fully coalesced; W/b are L1-resident.
// ---------------------------------------------------------------------------
__global__ __launch_bounds__(256) void expand_kernel(
    const float* __restrict__ hfd, const float* __restrict__ W,
    const float* __restrict__ b, float4* __restrict__ out, int total4) {
    const int gid = blockIdx.x * blockDim.x + threadIdx.x;
    if (gid >= total4) return;
    const int p  = gid >> 7;   // HIDDEN/4 = 128 float4 per position
    const int h4 = gid & 127;
    const float h = hfd[p];
    const float4 Wv = reinterpret_cast<const float4*>(W)[h4];
    const float4 bv = reinterpret_cast<const float4*>(b)[h4];
    float4 o;
    o.x = fmaxf(fmaf(h, Wv.x, bv.x), 0.0f);
    o.y = fmaxf(fmaf(h, Wv.y, bv.y), 0.0f);
    o.z = fmaxf(fmaf(h, Wv.z, bv.z), 0.0f);
    o.w = fmaxf(fmaf(h, Wv.w, bv.w), 0.0f);
    out[gid] = o;
}

extern "C" void kernel_launch(void* const* d_in, const int* in_sizes, int n_in,
                              void* d_out, int out_size, void* d_ws,
                              size_t ws_size, hipStream_t stream) {
    const float* x = (const float*)d_in[0];  // (16, 4096, 8)
    const float* W = (const float*)d_in[1];  // (512, 1)
    const float* b = (const float*)d_in[2];  // (512,)
    float* out = (float*)d_out;              // (16, 4096, 512) fp32

    const int P = in_sizes[0] / 8;           // 65536 positions
    float* hfd = (float*)d_ws;               // P floats of scratch (256 KB)

    fd_kernel<<<(P + BLK - 1) / BLK, BLK, 0, stream>>>(x, hfd, P);

    const int total4 = P * (HIDDEN / 4);     // 8,388,608 float4 stores
    expand_kernel<<<(total4 + 255) / 256, 256, 0, stream>>>(
        hfd, W, b, (float4*)out, total4);
}